// Round 22
// baseline (207.634 us; speedup 1.0000x reference)
//
#include <hip/hip_runtime.h>
#include <hip/hip_bf16.h>
#include <math.h>

#define NBT 32      // B*T
#define BB 2
#define TT 16
#define DD 64
#define CC 128
#define HH 48
#define WW2 48
#define HW 2304
#define NEXP 4
#define FF 256
#define EPS 1e-5f
#define PADROWS 2432   // 64 + 2304 + 64 padded pixel rows per image

typedef __attribute__((ext_vector_type(8))) short bf16x8;
typedef __attribute__((ext_vector_type(4))) float f32x4;
typedef __attribute__((ext_vector_type(4))) unsigned int uint4v;
typedef __attribute__((ext_vector_type(2))) unsigned int uint2v;

static __device__ __forceinline__ unsigned short f2bf(float v) {
  __hip_bfloat16 h = __float2bfloat16(v);
  return *(unsigned short*)&h;
}
static __device__ __forceinline__ float bf2f(unsigned short s) {
  unsigned int u = ((unsigned int)s) << 16;
  return *(float*)&u;
}

#define GLOAD_LDS16(gsrc, ldst) \
  __builtin_amdgcn_global_load_lds((const __attribute__((address_space(1))) unsigned int*)(gsrc), \
                                   (__attribute__((address_space(3))) unsigned int*)(ldst), 16, 0, 0)

// ---------------- K0: fused prep + LN1 — pads/xm + all weight transforms + LayerNorm ----------------
__global__ void k_prepln(unsigned int* __restrict__ xnb_u, float* __restrict__ xm,
                         const float* __restrict__ wc_re, const float* __restrict__ wc_im,
                         unsigned short* __restrict__ Wt,
                         const float* __restrict__ W1, const float* __restrict__ W2,
                         unsigned short* __restrict__ W1t, unsigned short* __restrict__ W2t,
                         const float* __restrict__ Einv_re, const float* __restrict__ Einv_im,
                         unsigned short* __restrict__ Bdt,
                         const float* __restrict__ E_re, const float* __restrict__ E_im,
                         unsigned short* __restrict__ Bet,
                         const float* __restrict__ x_re, const float* __restrict__ x_im,
                         const float* __restrict__ g, const float* __restrict__ b,
                         unsigned short* __restrict__ xnb) {
  int blk = blockIdx.x;
  int tid = threadIdx.x;
  if (blk < 1024) {
    int u = blk * 256 + tid;
    if (u < 4096) xm[u] = 0.f;            // xm_re (2048) + xm_im (2048), contiguous
    if (u >= 32 * 128 * 64) return;
    int img = u >> 13;
    int rem = u & 8191;
    int row = rem >> 6;
    int cu  = rem & 63;
    int prow = row < 64 ? row : row + 2304;
    xnb_u[((size_t)img * PADROWS + prow) * 64 + cu] = 0u;
  } else if (blk < 1600) {
    int idx = (blk - 1024) * 256 + tid;   // 147456
    int tap = idx / 16384;
    int rem = idx & 16383;
    int cout = rem >> 7, cin = rem & 127;
    float v;
    if (cout < 64) {
      if (cin < 64) v =  wc_re[((size_t)cout * 64 + cin) * 9 + tap];
      else          v = -wc_im[((size_t)cout * 64 + (cin - 64)) * 9 + tap];
    } else {
      int o = cout - 64;
      if (cin < 64) v =  wc_im[((size_t)o * 64 + cin) * 9 + tap];
      else          v =  wc_re[((size_t)o * 64 + (cin - 64)) * 9 + tap];
    }
    Wt[idx] = f2bf(v);
  } else if (blk < 2112) {
    int idx = (blk - 1600) * 256 + tid;   // 131072
    {
      int e = idx >> 15, rem = idx & 32767, j = rem >> 7, k = rem & 127;
      float v = W1[((size_t)e * 128 + k) * 256 + j];
      int sw = ((((k >> 3) ^ (j & 7)) << 3) | (k & 7));
      W1t[(size_t)e * 32768 + j * 128 + sw] = f2bf(v);
    }
    {
      int e = idx >> 15, rem = idx & 32767, c = rem >> 8, k2 = rem & 255;
      float v = W2[((size_t)e * 256 + k2) * 128 + c];
      int sw = ((((k2 >> 3) ^ (c & 7)) << 3) | (k2 & 7));
      W2t[(size_t)e * 32768 + c * 256 + sw] = f2bf(v);
    }
  } else if (blk < 2176) {
    int idx = (blk - 2112) * 256 + tid;   // 16384
    int j = idx >> 7, k = idx & 127;
    float v;
    if (j < 64) {
      if (k < 64) v =  Einv_re[k * 64 + j];
      else        v = -Einv_im[(k - 64) * 64 + j];
    } else {
      int d = j - 64;
      if (k < 64) v =  Einv_im[k * 64 + d];
      else        v =  Einv_re[(k - 64) * 64 + d];
    }
    int sw = ((((k >> 3) ^ (j & 7)) << 3) | (k & 7));
    Bdt[j * 128 + sw] = f2bf(v);
  } else if (blk < 2240) {
    int idx = (blk - 2176) * 256 + tid;   // 16384
    int j = idx >> 7, k = idx & 127;
    float v;
    if (j < 64) {
      if (k < 64) v =  E_re[k * 64 + j];
      else        v = -E_im[(k - 64) * 64 + j];
    } else {
      int d = j - 64;
      if (k < 64) v =  E_im[k * 64 + d];
      else        v =  E_re[(k - 64) * 64 + d];
    }
    int sw = ((((k >> 3) ^ (j & 7)) << 3) | (k & 7));
    Bet[j * 128 + sw] = f2bf(v);
  } else {
    // ---- LayerNorm branch, 1152 blocks ----
    int lb = blk - 2240;
    int n = lb / 36;
    int hw0 = (lb % 36) * 64;
    __shared__ float ls[64][129];
    __shared__ float part_s[4][64], part_q[4][64];
    __shared__ float mean_s[64], rstd_s[64];
    for (int i = tid; i < 64 * 128; i += 256) {
      int d = i >> 6, p = i & 63;
      float v = (d < DD) ? x_re[((size_t)n * DD + d) * HW + hw0 + p]
                         : x_im[((size_t)n * DD + (d - DD)) * HW + hw0 + p];
      ls[p][d] = v;
    }
    __syncthreads();
    {
      int p = tid & 63, q = tid >> 6;
      float s = 0.f, ss = 0.f;
      for (int c = q * 32; c < q * 32 + 32; c++) { float v = ls[p][c]; s += v; ss += v * v; }
      part_s[q][p] = s; part_q[q][p] = ss;
    }
    __syncthreads();
    if (tid < 64) {
      float s = part_s[0][tid] + part_s[1][tid] + part_s[2][tid] + part_s[3][tid];
      float ss = part_q[0][tid] + part_q[1][tid] + part_q[2][tid] + part_q[3][tid];
      float m = s * (1.f / CC);
      float var = ss * (1.f / CC) - m * m;
      mean_s[tid] = m; rstd_s[tid] = rsqrtf(var + EPS);
    }
    __syncthreads();
    for (int i = tid; i < 64 * 128; i += 256) {
      int p = i >> 7, c = i & 127;
      float v = (ls[p][c] - mean_s[p]) * rstd_s[p] * g[c] + b[c];
      xnb[(((size_t)n * PADROWS) + 64 + hw0 + p) * 128 + c] = f2bf(v);
    }
  }
}

// ---------------- K2: MFMA implicit-GEMM conv + FUSED eigen transform + mean partial ----------------
#define TM 128
#define AROWS 226

__global__ __launch_bounds__(512, 1) void k_conv(
    const unsigned short* __restrict__ xnb,
    const unsigned short* __restrict__ Wt,
    const float* __restrict__ bc_re, const float* __restrict__ bc_im,
    const float* __restrict__ metric,
    const float* __restrict__ x_re, const float* __restrict__ x_im,
    unsigned short* __restrict__ xpb,
    const unsigned short* __restrict__ Bet,
    unsigned short* __restrict__ egb_re, unsigned short* __restrict__ egb_im,
    float* __restrict__ xm_re, float* __restrict__ xm_im) {
  __shared__ unsigned short As[AROWS * 128];
  __shared__ unsigned short Bs[2][128 * 128];
  int n = blockIdx.x / 18;
  int tile = blockIdx.x % 18;
  int hw0 = tile * TM;
  int tid = threadIdx.x;
  int lane = tid & 63, wv = tid >> 6;
  int wvp = wv >> 1, wvc = wv & 1;
  int r16 = lane & 15, kgrp = lane >> 4;

  const unsigned short* xbase = xnb + ((size_t)n * PADROWS + 64 + hw0 - 49) * 128;
  for (int i = tid; i < AROWS * 16; i += 512) {
    int row = i >> 4, ch = i & 15;
    GLOAD_LDS16(xbase + (size_t)row * 128 + ((ch ^ (row & 7)) << 3), &As[i * 8]);
  }
  {
    #pragma unroll
    for (int it = 0; it < 4; it++) {
      int i = it * 512 + tid;
      int row = i >> 4, ch = i & 15;
      GLOAD_LDS16(Wt + (size_t)row * 128 + ((ch ^ (row & 7)) << 3), &Bs[0][i * 8]);
    }
  }

  f32x4 acc[2][4];
  #pragma unroll
  for (int am = 0; am < 2; am++)
    #pragma unroll
    for (int n0 = 0; n0 < 4; n0++) acc[am][n0] = (f32x4){0.f, 0.f, 0.f, 0.f};

  int w0 = (hw0 + wvp * 32 + r16) % 48;
  int w1 = (hw0 + wvp * 32 + 16 + r16) % 48;

  __syncthreads();   // As + Bs[0] staged (vmcnt drained)

  for (int tap = 0; tap < 9; tap++) {
    int cur = tap & 1;
    if (tap < 8) {
      const unsigned short* wbase = Wt + (size_t)(tap + 1) * 16384;
      #pragma unroll
      for (int it = 0; it < 4; it++) {
        int i = it * 512 + tid;
        int row = i >> 4, ch = i & 15;
        GLOAD_LDS16(wbase + (size_t)row * 128 + ((ch ^ (row & 7)) << 3), &Bs[cur ^ 1][i * 8]);
      }
    }
    int ky = tap / 3, kx = tap % 3;
    int delta = (ky - 1) * 48 + (kx - 1);
    bool v0 = (unsigned)(w0 + kx - 1) < 48u;
    bool v1 = (unsigned)(w1 + kx - 1) < 48u;
    int lp0 = wvp * 32 + r16 + delta + 49;
    int lp1 = lp0 + 16;
    __builtin_amdgcn_s_setprio(1);
    #pragma unroll
    for (int k0 = 0; k0 < 4; k0++) {
      bf16x8 a0 = {0,0,0,0,0,0,0,0}, a1 = {0,0,0,0,0,0,0,0};
      if (v0) a0 = *(const bf16x8*)(As + lp0 * 128 + (((k0 * 4 + kgrp) ^ (lp0 & 7)) << 3));
      if (v1) a1 = *(const bf16x8*)(As + lp1 * 128 + (((k0 * 4 + kgrp) ^ (lp1 & 7)) << 3));
      #pragma unroll
      for (int n0 = 0; n0 < 4; n0++) {
        int brow = wvc * 64 + n0 * 16 + r16;
        bf16x8 b = *(const bf16x8*)(&Bs[cur][brow * 128 + (((k0 * 4 + kgrp) ^ (brow & 7)) << 3)]);
        acc[0][n0] = __builtin_amdgcn_mfma_f32_16x16x32_bf16(a0, b, acc[0][n0], 0, 0, 0);
        acc[1][n0] = __builtin_amdgcn_mfma_f32_16x16x32_bf16(a1, b, acc[1][n0], 0, 0, 0);
      }
    }
    __builtin_amdgcn_s_setprio(0);
    __syncthreads();   // MFMA(tap) done + Bs[next] loads drained
  }

  // ---- issue Bet staging into dead As region (overlaps epilogue below) ----
  {
    #pragma unroll
    for (int it = 0; it < 4; it++)
      GLOAD_LDS16(Bet + (size_t)(it * 512 + tid) * 8, &As[(it * 512 + tid) * 8]);
  }
  float* red = (float*)&As[16384];   // 128 f32 mean scratch (beyond Bet's 32KB)
  if (tid < 128) red[tid] = 0.f;

  // ---- conv epilogue: bf16 xp write + bf16 -> Xe (dead Bs[0], swizzled) ----
  unsigned short* Xe = &Bs[0][0];
  #pragma unroll
  for (int am = 0; am < 2; am++) {
    int prow0 = wvp * 32 + am * 16 + kgrp * 4;
    int pix0 = hw0 + prow0;
    f32x4 mets = *(const f32x4*)(metric + pix0);
    #pragma unroll
    for (int n0 = 0; n0 < 4; n0++) {
      int col = wvc * 64 + n0 * 16 + r16;
      float bias = (col < DD) ? bc_re[col] : bc_im[col - DD];
      const float* xsrc = (col < DD) ? (x_re + ((size_t)n * DD + col) * HW)
                                     : (x_im + ((size_t)n * DD + (col - DD)) * HW);
      f32x4 xres = *(const f32x4*)(xsrc + pix0);
      #pragma unroll
      for (int j = 0; j < 4; j++) {
        float v = acc[am][n0][j] * mets[j] + bias + xres[j];
        unsigned short bv = f2bf(v);
        xpb[((size_t)n * HW + pix0 + j) * 128 + col] = bv;
        int pix = prow0 + j;
        Xe[pix * 128 + ((((col >> 3) ^ (pix & 7)) << 3) | (col & 7))] = bv;
      }
    }
  }
  __syncthreads();   // Xe visible + Bet drained + red zeroed

  // ---- eigen GEMM: 8 waves = 2 pos-halves x (2x2) wave grid ----
  {
    const unsigned short* BetL = (const unsigned short*)As;
    int half = wv >> 2, wmE = (wv >> 1) & 1, wnE = wv & 1;
    f32x4 accE[2][4];
    #pragma unroll
    for (int mt = 0; mt < 2; mt++)
      #pragma unroll
      for (int nt = 0; nt < 4; nt++) accE[mt][nt] = (f32x4){0.f, 0.f, 0.f, 0.f};
    #pragma unroll
    for (int ks = 0; ks < 4; ks++) {
      int kc = ks * 4 + kgrp;
      bf16x8 a[2], bb[4];
      #pragma unroll
      for (int mt = 0; mt < 2; mt++) {
        int r = half * 64 + wmE * 32 + mt * 16 + r16;
        a[mt] = *(const bf16x8*)&Xe[r * 128 + ((kc ^ (r & 7)) << 3)];
      }
      #pragma unroll
      for (int nt = 0; nt < 4; nt++) {
        int j = wnE * 64 + nt * 16 + r16;
        bb[nt] = *(const bf16x8*)&BetL[j * 128 + ((kc ^ (j & 7)) << 3)];
      }
      #pragma unroll
      for (int mt = 0; mt < 2; mt++)
        #pragma unroll
        for (int nt = 0; nt < 4; nt++)
          accE[mt][nt] = __builtin_amdgcn_mfma_f32_16x16x32_bf16(a[mt], bb[nt], accE[mt][nt], 0, 0, 0);
    }
    #pragma unroll
    for (int nt = 0; nt < 4; nt++) {
      int j2 = wnE * 64 + nt * 16 + r16;
      float psum = 0.f;
      #pragma unroll
      for (int mt = 0; mt < 2; mt++) {
        int row0 = half * 64 + wmE * 32 + mt * 16 + kgrp * 4;
        #pragma unroll
        for (int jj = 0; jj < 4; jj++) {
          float v = accE[mt][nt][jj];
          size_t pos = (size_t)n * HW + hw0 + row0 + jj;
          if (j2 < 64) egb_re[pos * 64 + j2] = f2bf(v);
          else         egb_im[pos * 64 + (j2 - 64)] = f2bf(v);
          psum += v;
        }
      }
      atomicAdd(&red[j2], psum);
    }
  }
  __syncthreads();
  if (tid < 128) {
    float val = red[tid] * (1.f / HW);
    if (tid < 64) atomicAdd(&xm_re[n * DD + tid], val);
    else          atomicAdd(&xm_im[n * DD + (tid - 64)], val);
  }
}

// ---------------- K5: fused flux scan + per-(b,t) src/gate matmul + od/of ----------------
__global__ void k_seq(const float* __restrict__ xm_re, const float* __restrict__ xm_im,
                      const float* __restrict__ dt, const float* __restrict__ lam_flux,
                      const float* __restrict__ inj_re, const float* __restrict__ inj_im,
                      const float* __restrict__ flux_re0, const float* __restrict__ flux_im0,
                      const float* __restrict__ Wsrc_re, const float* __restrict__ Wsrc_im,
                      const float* __restrict__ Wgate, const float* __restrict__ bgate,
                      const float* __restrict__ lam_re, const float* __restrict__ lam_im,
                      float* __restrict__ gate, float* __restrict__ src_re, float* __restrict__ src_im,
                      float* __restrict__ od_re, float* __restrict__ od_im,
                      float* __restrict__ of_re, float* __restrict__ of_im) {
  int bt = blockIdx.x;
  int b = bt / TT;
  int t = bt % TT;
  int e = threadIdx.x;
  __shared__ float fr[DD], fi[DD];
  {
    float lx = lam_flux[e];
    float sp = lx > 20.f ? lx : log1pf(expf(lx));
    float f_r = flux_re0[b * DD + e], f_i = flux_im0[b * DD + e];
    float ij_r = inj_re[e], ij_i = inj_im[e];
    for (int tp = 0; tp <= t; tp++) {
      float A = expf(-sp * dt[tp]);
      int btp = b * TT + tp;
      float xr = xm_re[btp * DD + e], xi = xm_im[btp * DD + e];
      f_r = A * f_r + (xr * ij_r - xi * ij_i);
      f_i = A * f_i + (xr * ij_i + xi * ij_r);
    }
    fr[e] = f_r; fi[e] = f_i;
  }
  __syncthreads();
  float sr = 0.f, si = 0.f, gl = bgate[e];
  for (int d2 = 0; d2 < DD; d2++) {
    float r = fr[d2], im = fi[d2];
    float wr = Wsrc_re[d2 * DD + e], wi = Wsrc_im[d2 * DD + e];
    sr += r * wr - im * wi;
    si += r * wi + im * wr;
    gl += r * Wgate[d2 * DD + e];
  }
  src_re[bt * DD + e] = sr; src_im[bt * DD + e] = si;
  gate[bt * DD + e] = 1.f / (1.f + expf(-gl));
  float lre = lam_re[e];
  float lr_v = -(lre > 20.f ? lre : log1pf(expf(lre)));
  float li_v = lam_im[e];
  float den = lr_v * lr_v + li_v * li_v;
  float dtv = dt[t];
  float mag = expf(lr_v * dtv);
  float odr = mag * cosf(li_v * dtv);
  float odi = mag * sinf(li_v * dtv);
  od_re[bt * DD + e] = odr; od_im[bt * DD + e] = odi;
  of_re[bt * DD + e] = ((odr - 1.f) * lr_v + odi * li_v) / den;
  of_im[bt * DD + e] = (odi * lr_v - (odr - 1.f) * li_v) / den;
}

// ---------------- K6: forcing + time scan; bf16 eg in, pre-swizzled bf16 ub out ----------------
__global__ void k_uscan(const unsigned short* __restrict__ egb_re,
                        const unsigned short* __restrict__ egb_im,
                        unsigned short* __restrict__ ub,
                        const float* __restrict__ gate,
                        const float* __restrict__ src_re, const float* __restrict__ src_im,
                        const float* __restrict__ od_re, const float* __restrict__ od_im,
                        const float* __restrict__ of_re, const float* __restrict__ of_im,
                        const float* __restrict__ h_re, const float* __restrict__ h_im) {
  size_t gid = (size_t)blockIdx.x * 256 + threadIdx.x;
  int e = (int)(gid & 63);
  size_t rem = gid >> 6;
  int hw = (int)(rem % HW);
  int b = (int)(rem / HW);
  float u_r = 0.f, u_i = 0.f;
  for (int t = 0; t < TT; t++) {
    int bt = b * TT + t;
    size_t idx = ((size_t)bt * HW + hw) * DD + e;
    float g = gate[bt * DD + e];
    float fr2 = bf2f(egb_re[idx]) * g + src_re[bt * DD + e] * (1.f - g);
    float fi2 = bf2f(egb_im[idx]) * g + src_im[bt * DD + e] * (1.f - g);
    float ofr = of_re[bt * DD + e], ofi = of_im[bt * DD + e];
    float ut_r = fr2 * ofr - fi2 * ofi;
    float ut_i = fr2 * ofi + fi2 * ofr;
    float odr = od_re[bt * DD + e], odi = od_im[bt * DD + e];
    if (t == 0) {
      size_t hidx = ((size_t)b * HW + hw) * DD + e;
      float hr = h_re[hidx], hi = h_im[hidx];
      ut_r += hr * odr - hi * odi;
      ut_i += hr * odi + hi * odr;
    }
    float nu_r = odr * u_r - odi * u_i + ut_r;
    float nu_i = odr * u_i + odi * u_r + ut_i;
    u_r = nu_r; u_i = nu_i;
    size_t pos = (size_t)bt * HW + hw;
    int p7 = (int)(pos & 7);
    int swr = (((e >> 3) ^ p7) << 3) | (e & 7);
    int swi = ((((64 + e) >> 3) ^ p7) << 3) | (e & 7);
    ub[pos * 128 + swr] = f2bf(u_r);
    ub[pos * 128 + swi] = f2bf(u_i);
  }
}

// ---------------- K78: FUSED decode(MFMA)+LN2+gates + MFMA MoE; 128 pos / 512 thr ----------------
// Doubled tile: weight staging (512KB/block) and the 18 barriers now amortize
// over 2x positions. Yl eliminated: acc2 initializes from the bf16 Xb copy of y
// (y rounded to bf16 in the residual path; delta path unchanged).
// LDS (98304): phaseD {BdL[0,32K) Au[32K,64K)} -> DsD[0,64K) -> Xb[64K,96K)
//              MoE {W1s[0,32K) W2s[32K,64K) Hs[64K,96K)}  epilogue Ds 128x129 f32.
__global__ __launch_bounds__(512, 1) void k_dmoe(
    const unsigned short* __restrict__ ub,
    const unsigned short* __restrict__ Bdt,
    const float* __restrict__ Wg,
    float* __restrict__ gates,
    const unsigned short* __restrict__ xpb,
    const unsigned short* __restrict__ W1t, const unsigned short* __restrict__ W2t,
    const float* __restrict__ b1, const float* __restrict__ b2,
    const float* __restrict__ gt_g, const float* __restrict__ gt_b,
    float* __restrict__ out) {
  __shared__ __attribute__((aligned(16))) unsigned char smem[98304];
  int tid = threadIdx.x;
  int blk = blockIdx.x;
  int n = blk / 18;
  int hw0 = (blk % 18) * 128;
  size_t pos0 = (size_t)blk * 128;
  int lane = tid & 63, w = tid >> 6, wm = w >> 1, wn = w & 1;   // wm 0..3, wn 0..1
  int r16 = lane & 15, kgrp = lane >> 4;

  // ================= Phase D: MFMA decode + LN2 + gates; X -> Xb (bf16 y) =================
  {
    unsigned short* BdL = (unsigned short*)smem;            // 32 KB [j][k sw]
    unsigned short* Au  = (unsigned short*)(smem + 32768);  // 32 KB [p(128)][k sw]
    #pragma unroll
    for (int it = 0; it < 4; it++)
      GLOAD_LDS16(Bdt + (size_t)(it * 512 + tid) * 8, &BdL[(it * 512 + tid) * 8]);
    #pragma unroll
    for (int it = 0; it < 4; it++)
      GLOAD_LDS16(ub + pos0 * 128 + (size_t)(it * 512 + tid) * 8, &Au[(it * 512 + tid) * 8]);
    __syncthreads();   // Au + BdL staged (vmcnt drained by syncthreads)
    f32x4 accD[2][4];
    #pragma unroll
    for (int mt = 0; mt < 2; mt++)
      #pragma unroll
      for (int nt = 0; nt < 4; nt++) accD[mt][nt] = (f32x4){0.f, 0.f, 0.f, 0.f};
    #pragma unroll
    for (int ks = 0; ks < 4; ks++) {
      int kc = ks * 4 + kgrp;
      bf16x8 a[2], bb[4];
      #pragma unroll
      for (int mt = 0; mt < 2; mt++) {
        int r = wm * 32 + mt * 16 + r16;
        a[mt] = *(const bf16x8*)&Au[r * 128 + ((kc ^ (r & 7)) << 3)];
      }
      #pragma unroll
      for (int nt = 0; nt < 4; nt++) {
        int j = wn * 64 + nt * 16 + r16;
        bb[nt] = *(const bf16x8*)&BdL[j * 128 + ((kc ^ (j & 7)) << 3)];
      }
      #pragma unroll
      for (int mt = 0; mt < 2; mt++)
        #pragma unroll
        for (int nt = 0; nt < 4; nt++)
          accD[mt][nt] = __builtin_amdgcn_mfma_f32_16x16x32_bf16(a[mt], bb[nt], accD[mt][nt], 0, 0, 0);
    }
    __syncthreads();   // all Au/BdL reads done — regions reusable
    float* DsD = (float*)smem;                      // 64 KB [p(128)][c] linear
    #pragma unroll
    for (int mt = 0; mt < 2; mt++) {
      int row0 = wm * 32 + mt * 16 + kgrp * 4;
      #pragma unroll
      for (int nt = 0; nt < 4; nt++) {
        int c = wn * 64 + nt * 16 + r16;
        #pragma unroll
        for (int jj = 0; jj < 4; jj++)
          DsD[(row0 + jj) * 128 + c] = accD[mt][nt][jj];
      }
    }
    __syncthreads();   // C in LDS
    unsigned short* Xb = (unsigned short*)(smem + 65536);  // 32 KB
    int egq = tid & 15, pg = tid >> 4;   // pg 0..31
    int d0 = egq * 4;
    f32x4 gg0 = *(const f32x4*)(gt_g + d0);
    f32x4 gb0 = *(const f32x4*)(gt_b + d0);
    f32x4 gg1 = *(const f32x4*)(gt_g + 64 + d0);
    f32x4 gb1 = *(const f32x4*)(gt_b + 64 + d0);
    f32x4 wgr[4], wgi[4];
    #pragma unroll
    for (int j = 0; j < 4; j++) {
      wgr[j] = *(const f32x4*)&Wg[(d0 + j) * 4];
      wgi[j] = *(const f32x4*)&Wg[(64 + d0 + j) * 4];
    }
    #pragma unroll
    for (int i = 0; i < 4; i++) {
      int p = pg + 32 * i;
      size_t pos = pos0 + p;
      int swz = p & 7;
      int cre = ((d0 >> 3) ^ swz) << 3;
      int cim = (((64 + d0) >> 3) ^ swz) << 3;
      int off47 = d0 & 7;   // 0 or 4
      f32x4 acr = *(const f32x4*)&DsD[p * 128 + d0];
      f32x4 aci = *(const f32x4*)&DsD[p * 128 + 64 + d0];
      float s = acr[0] + acr[1] + acr[2] + acr[3]
              + aci[0] + aci[1] + aci[2] + aci[3];
      float q = acr[0]*acr[0] + acr[1]*acr[1] + acr[2]*acr[2] + acr[3]*acr[3]
              + aci[0]*aci[0] + aci[1]*aci[1] + aci[2]*aci[2] + aci[3]*aci[3];
      #pragma unroll
      for (int off = 8; off >= 1; off >>= 1) {
        s += __shfl_xor(s, off);
        q += __shfl_xor(q, off);
      }
      float mean = s * (1.f / CC);
      float rstd = rsqrtf(q * (1.f / CC) - mean * mean + EPS);
      f32x4 lnr = (acr - mean) * rstd * gg0 + gb0;
      f32x4 lni = (aci - mean) * rstd * gg1 + gb1;
      f32x4 p4 = lnr[0]*wgr[0] + lnr[1]*wgr[1] + lnr[2]*wgr[2] + lnr[3]*wgr[3]
               + lni[0]*wgi[0] + lni[1]*wgi[1] + lni[2]*wgi[2] + lni[3]*wgi[3];
      float p0 = p4[0], p1 = p4[1], p2 = p4[2], p3 = p4[3];
      #pragma unroll
      for (int off = 8; off >= 1; off >>= 1) {
        p0 += __shfl_xor(p0, off); p1 += __shfl_xor(p1, off);
        p2 += __shfl_xor(p2, off); p3 += __shfl_xor(p3, off);
      }
      if (egq == 0) {
        float m = fmaxf(fmaxf(p0, p1), fmaxf(p2, p3));
        float e0v = __expf(p0 - m), e1v = __expf(p1 - m), e2v = __expf(p2 - m), e3v = __expf(p3 - m);
        float inv = 1.f / (e0v + e1v + e2v + e3v);
        f32x4 g4 = {e0v * inv, e1v * inv, e2v * inv, e3v * inv};
        *(f32x4*)(gates + pos * 4) = g4;
      }
      unsigned int r0 = (unsigned int)f2bf(lnr[0]) | ((unsigned int)f2bf(lnr[1]) << 16);
      unsigned int r1 = (unsigned int)f2bf(lnr[2]) | ((unsigned int)f2bf(lnr[3]) << 16);
      unsigned int i0 = (unsigned int)f2bf(lni[0]) | ((unsigned int)f2bf(lni[1]) << 16);
      unsigned int i1 = (unsigned int)f2bf(lni[2]) | ((unsigned int)f2bf(lni[3]) << 16);
      *(uint2v*)&Xb[p * 128 + cre + off47] = (uint2v){r0, r1};
      *(uint2v*)&Xb[p * 128 + cim + off47] = (uint2v){i0, i1};
    }
  }
  __syncthreads();   // Xb complete; gates globally visible

  // ================= Transition: acc2 <- bf16 y (Xb); xa <- Xb; stage W1[0] =================
  unsigned short* W1s = (unsigned short*)smem;             // 32 KB (over DsD lower)
  unsigned short* W2s = (unsigned short*)(smem + 32768);   // 32 KB (over DsD upper)
  unsigned short* Hs  = (unsigned short*)(smem + 65536);   // 32 KB (over Xb after read)
  float* Ds = (float*)smem;                                // 66 KB, reused after MoE loop
  f32x4 acc2[2][4];
  bf16x8 xa[2][4];   // [pt][ks]
  {
    const unsigned short* Xb = (const unsigned short*)(smem + 65536);
    #pragma unroll
    for (int mt = 0; mt < 2; mt++) {
      int row0 = wm * 32 + mt * 16 + kgrp * 4;
      #pragma unroll
      for (int nt = 0; nt < 4; nt++) {
        int c = wn * 64 + nt * 16 + r16;
        #pragma unroll
        for (int jj = 0; jj < 4; jj++) {
          int row = row0 + jj;
          acc2[mt][nt][jj] = bf2f(Xb[row * 128 + ((((c >> 3) ^ (row & 7)) << 3) | (c & 7))]);
        }
      }
    }
    #pragma unroll
    for (int pt = 0; pt < 2; pt++) {
      int r = wm * 32 + pt * 16 + r16;
      #pragma unroll
      for (int ks = 0; ks < 4; ks++) {
        int kc = ks * 4 + kgrp;
        xa[pt][ks] = *(const bf16x8*)&Xb[r * 128 + ((kc ^ (r & 7)) << 3)];
      }
    }
  }
  __syncthreads();   // Xb reads done — safe to overwrite
  {
    #pragma unroll
    for (int it = 0; it < 4; it++)
      GLOAD_LDS16(W1t + (size_t)(it * 512 + tid) * 8, &W1s[(it * 512 + tid) * 8]);
  }
  __syncthreads();   // W1[0] drained

  // ================= Phase M: MoE loop (acc2 pre-loaded with y) =================
  const float c1 = -2.3022084f;
  const float c2 = -0.10294372f;

  for (int s = 0; s < 8; s++) {
    int e = s >> 1, h = s & 1;
    float grp[2];
    #pragma unroll
    for (int pt = 0; pt < 2; pt++)
      grp[pt] = gates[(pos0 + wm * 32 + pt * 16 + r16) * 4 + e];
    f32x4 b1p[4];
    #pragma unroll
    for (int ft = 0; ft < 4; ft++)
      b1p[ft] = *(const f32x4*)&b1[e * 256 + h * 128 + wn * 64 + ft * 16 + kgrp * 4];
    {
      const unsigned short* w2src = W2t + (size_t)e * 32768 + (size_t)h * 128;
      #pragma unroll
      for (int it = 0; it < 4; it++) {
        int i = it * 512 + tid;
        int c = i >> 4, j = i & 15;
        GLOAD_LDS16(w2src + (size_t)c * 256 + j * 8, &W2s[i * 8]);
      }
    }
    f32x4 acc1[4][2];
    #pragma unroll
    for (int ft = 0; ft < 4; ft++)
      #pragma unroll
      for (int pt = 0; pt < 2; pt++) acc1[ft][pt] = (f32x4){0.f, 0.f, 0.f, 0.f};
    __builtin_amdgcn_s_setprio(1);
    #pragma unroll
    for (int ks = 0; ks < 4; ks++) {
      int kc = ks * 4 + kgrp;
      bf16x8 wf[4];
      #pragma unroll
      for (int ft = 0; ft < 4; ft++) {
        int fr = wn * 64 + ft * 16 + r16;
        wf[ft] = *(const bf16x8*)&W1s[fr * 128 + ((kc ^ (fr & 7)) << 3)];
      }
      #pragma unroll
      for (int ft = 0; ft < 4; ft++)
        #pragma unroll
        for (int pt = 0; pt < 2; pt++)
          acc1[ft][pt] = __builtin_amdgcn_mfma_f32_16x16x32_bf16(wf[ft], xa[pt][ks], acc1[ft][pt], 0, 0, 0);
    }
    __builtin_amdgcn_s_setprio(0);
    #pragma unroll
    for (int ft = 0; ft < 4; ft++) {
      int f0 = wn * 64 + ft * 16 + kgrp * 4;
      int chunk = f0 >> 3, sub = f0 & 7;
      #pragma unroll
      for (int pt = 0; pt < 2; pt++) {
        int pl = wm * 32 + pt * 16 + r16;
        float gr = grp[pt];
        unsigned short hb[4];
        #pragma unroll
        for (int jj = 0; jj < 4; jj++) {
          float x = acc1[ft][pt][jj] + b1p[ft][jj];
          float z = x * (c1 + c2 * x * x);
          float t = __builtin_amdgcn_exp2f(z);
          hb[jj] = f2bf(x * gr * __builtin_amdgcn_rcpf(1.f + t));
        }
        unsigned int lo = (unsigned int)hb[0] | ((unsigned int)hb[1] << 16);
        unsigned int hi = (unsigned int)hb[2] | ((unsigned int)hb[3] << 16);
        *(uint2v*)&Hs[pl * 128 + ((chunk ^ (pl & 7)) << 3) + sub] = (uint2v){lo, hi};
      }
    }
    __syncthreads();   // Hs ready; W2 stage drained; W1s consumed
    if (s < 7) {
      int sn = s + 1;
      const unsigned short* w1src = W1t + (size_t)(sn >> 1) * 32768 + (size_t)(sn & 1) * 16384;
      #pragma unroll
      for (int it = 0; it < 4; it++)
        GLOAD_LDS16(w1src + (size_t)(it * 512 + tid) * 8, &W1s[(it * 512 + tid) * 8]);
    }
    __builtin_amdgcn_s_setprio(1);
    #pragma unroll
    for (int ks = 0; ks < 4; ks++) {
      int kc = ks * 4 + kgrp;
      bf16x8 a[2], bb[4];
      #pragma unroll
      for (int mt = 0; mt < 2; mt++) {
        int r = wm * 32 + mt * 16 + r16;
        a[mt] = *(const bf16x8*)&Hs[r * 128 + ((kc ^ (r & 7)) << 3)];
      }
      #pragma unroll
      for (int nt = 0; nt < 4; nt++) {
        int c = wn * 64 + nt * 16 + r16;
        bb[nt] = *(const bf16x8*)&W2s[c * 128 + ((kc ^ (c & 7)) << 3)];
      }
      #pragma unroll
      for (int mt = 0; mt < 2; mt++)
        #pragma unroll
        for (int nt = 0; nt < 4; nt++)
          acc2[mt][nt] = __builtin_amdgcn_mfma_f32_16x16x32_bf16(a[mt], bb[nt], acc2[mt][nt], 0, 0, 0);
    }
    __builtin_amdgcn_s_setprio(0);
    __syncthreads();
  }

  // ---- LDS-transposed final epilogue (acc2 already holds y + delta) ----
  #pragma unroll
  for (int mt = 0; mt < 2; mt++) {
    int row0 = wm * 32 + mt * 16 + kgrp * 4;
    #pragma unroll
    for (int nt = 0; nt < 4; nt++) {
      int c = wn * 64 + nt * 16 + r16;
      #pragma unroll
      for (int jj = 0; jj < 4; jj++)
        Ds[(row0 + jj) * 129 + c] = acc2[mt][nt][jj];
    }
  }
  __syncthreads();
  #pragma unroll
  for (int it = 0; it < 8; it++) {
    int qi = it * 512 + tid;
    int p = qi >> 5, cq = (qi & 31) << 2;
    size_t pos = pos0 + p;
    const unsigned short* xr = &xpb[pos * 128 + cq];
    f32x4 xpv = {bf2f(xr[0]), bf2f(xr[1]), bf2f(xr[2]), bf2f(xr[3])};
    f32x4 g4  = *(const f32x4*)&gates[pos * 4];
    f32x4 bt0 = *(const f32x4*)&b2[0 * CC + cq];
    f32x4 bt1 = *(const f32x4*)&b2[1 * CC + cq];
    f32x4 bt2 = *(const f32x4*)&b2[2 * CC + cq];
    f32x4 bt3 = *(const f32x4*)&b2[3 * CC + cq];
    int base = p * 129 + cq;
    #pragma unroll
    for (int j = 0; j < 4; j++) {
      float bterm = g4[0] * bt0[j] + g4[1] * bt1[j] + g4[2] * bt2[j] + g4[3] * bt3[j];
      Ds[base + j] = xpv[j] + Ds[base + j] + bterm;
    }
  }
  __syncthreads();
  {
    int p = tid & 127;
    int cg = tid >> 7;
    const float* Drow = Ds + p * 129;
    size_t obase = ((size_t)n * CC) * HW + hw0 + p;
    #pragma unroll
    for (int i = 0; i < 32; i++) {
      int c = i * 4 + cg;
      out[obase + (size_t)c * HW] = Drow[c];
    }
  }
}

extern "C" void kernel_launch(void* const* d_in, const int* in_sizes, int n_in,
                              void* d_out, int out_size, void* d_ws, size_t ws_size,
                              hipStream_t stream) {
  const float* x_re   = (const float*)d_in[0];
  const float* x_im   = (const float*)d_in[1];
  const float* h_re   = (const float*)d_in[2];
  const float* h_im   = (const float*)d_in[3];
  const float* flux_re= (const float*)d_in[4];
  const float* flux_im= (const float*)d_in[5];
  const float* dt     = (const float*)d_in[6];
  const float* gs_g   = (const float*)d_in[7];
  const float* gs_b   = (const float*)d_in[8];
  const float* wc_re  = (const float*)d_in[9];
  const float* wc_im  = (const float*)d_in[10];
  const float* bc_re  = (const float*)d_in[11];
  const float* bc_im  = (const float*)d_in[12];
  const float* metric = (const float*)d_in[13];
  const float* gt_g   = (const float*)d_in[14];
  const float* gt_b   = (const float*)d_in[15];
  const float* E_re   = (const float*)d_in[16];
  const float* E_im   = (const float*)d_in[17];
  const float* Einv_re= (const float*)d_in[18];
  const float* Einv_im= (const float*)d_in[19];
  const float* lam_flux=(const float*)d_in[20];
  const float* inj_re = (const float*)d_in[21];
  const float* inj_im = (const float*)d_in[22];
  const float* Wsrc_re= (const float*)d_in[23];
  const float* Wsrc_im= (const float*)d_in[24];
  const float* Wgate  = (const float*)d_in[25];
  const float* bgate  = (const float*)d_in[26];
  const float* lam_re = (const float*)d_in[27];
  const float* lam_im = (const float*)d_in[28];
  const float* Wg     = (const float*)d_in[29];
  const float* W1     = (const float*)d_in[30];
  const float* b1     = (const float*)d_in[31];
  const float* W2     = (const float*)d_in[32];
  const float* b2     = (const float*)d_in[33];

  float* ws = (float*)d_ws;
  const size_t SZ_FULL = (size_t)NBT * HW * CC;   // 9,437,184
  const size_t SZ_HALF = (size_t)NBT * HW * DD;   // 4,718,592
  // Regions keep their f32-sized slots (layout unchanged); xp/eg hold bf16.
  float* xp    = ws;                    // bf16 [pos][128] (half-used slot)
  float* eg_re = xp + SZ_FULL;          // bf16 (half-used slot)
  float* eg_im = eg_re + SZ_HALF;       // bf16 (half-used slot)
  float* xr2   = eg_im + SZ_HALF;       // aliases xnb (bf16) + Wt (bf16) + ub (bf16)
  unsigned short* xnb = (unsigned short*)xr2;
  unsigned short* Wt  = (unsigned short*)(xr2 + 5000000);
  unsigned short* ub  = (unsigned short*)xr2;   // over xnb (dead after k_conv)
  float* smalls = xr2 + SZ_FULL;
  float* xm_re = smalls;
  float* xm_im = xm_re + 2048;
  float* gatep = xm_im + 2048;
  float* src_re= gatep + 2048;
  float* src_im= src_re + 2048;
  float* od_re = src_im + 2048;
  float* od_im = od_re + 2048;
  float* of_re = od_im + 2048;
  float* of_im = of_re + 2048;
  float* gates = of_im + 2048;
  unsigned short* W1t = (unsigned short*)(gates + (size_t)NBT * HW * 4);
  unsigned short* W2t = W1t + 131072;
  unsigned short* Bdt = W2t + 131072;   // 16384 bf16
  unsigned short* Bet = Bdt + 16384;    // 16384 bf16

  unsigned short* xpb    = (unsigned short*)xp;
  unsigned short* egb_re = (unsigned short*)eg_re;
  unsigned short* egb_im = (unsigned short*)eg_im;

  hipLaunchKernelGGL(k_prepln, dim3(3392), dim3(256), 0, stream,
                     (unsigned int*)xnb, xm_re, wc_re, wc_im, Wt, W1, W2, W1t, W2t,
                     Einv_re, Einv_im, Bdt, E_re, E_im, Bet,
                     x_re, x_im, gs_g, gs_b, xnb);
  hipLaunchKernelGGL(k_conv, dim3(NBT * 18), dim3(512), 0, stream,
                     xnb, Wt, bc_re, bc_im, metric, x_re, x_im, xpb,
                     Bet, egb_re, egb_im, xm_re, xm_im);
  hipLaunchKernelGGL(k_seq, dim3(NBT), dim3(DD), 0, stream,
                     xm_re, xm_im, dt, lam_flux, inj_re, inj_im, flux_re, flux_im,
                     Wsrc_re, Wsrc_im, Wgate, bgate, lam_re, lam_im,
                     gatep, src_re, src_im, od_re, od_im, of_re, of_im);
  hipLaunchKernelGGL(k_uscan, dim3(1152), dim3(256), 0, stream,
                     egb_re, egb_im, ub, gatep, src_re, src_im, od_re, od_im, of_re, of_im,
                     h_re, h_im);
  hipLaunchKernelGGL(k_dmoe, dim3(576), dim3(512), 0, stream,
                     ub, Bdt, Wg,
                     gates, xpb, W1t, W2t, b1, b2, gt_g, gt_b,
                     (float*)d_out);
}

// Round 23
// 191.879 us; speedup vs baseline: 1.0821x; 1.0821x over previous
//
#include <hip/hip_runtime.h>
#include <hip/hip_bf16.h>
#include <math.h>

#define NBT 32      // B*T
#define BB 2
#define TT 16
#define DD 64
#define CC 128
#define HH 48
#define WW2 48
#define HW 2304
#define NEXP 4
#define FF 256
#define EPS 1e-5f
#define PADROWS 2432   // 64 + 2304 + 64 padded pixel rows per image

typedef __attribute__((ext_vector_type(8))) short bf16x8;
typedef __attribute__((ext_vector_type(4))) float f32x4;
typedef __attribute__((ext_vector_type(4))) unsigned int uint4v;
typedef __attribute__((ext_vector_type(2))) unsigned int uint2v;

static __device__ __forceinline__ unsigned short f2bf(float v) {
  __hip_bfloat16 h = __float2bfloat16(v);
  return *(unsigned short*)&h;
}
static __device__ __forceinline__ float bf2f(unsigned short s) {
  unsigned int u = ((unsigned int)s) << 16;
  return *(float*)&u;
}

#define GLOAD_LDS16(gsrc, ldst) \
  __builtin_amdgcn_global_load_lds((const __attribute__((address_space(1))) unsigned int*)(gsrc), \
                                   (__attribute__((address_space(3))) unsigned int*)(ldst), 16, 0, 0)

// ---------------- K0: fused prep + LN1 — pads/xm + all weight transforms + LayerNorm ----------------
__global__ void k_prepln(unsigned int* __restrict__ xnb_u, float* __restrict__ xm,
                         const float* __restrict__ wc_re, const float* __restrict__ wc_im,
                         unsigned short* __restrict__ Wt,
                         const float* __restrict__ W1, const float* __restrict__ W2,
                         unsigned short* __restrict__ W1t, unsigned short* __restrict__ W2t,
                         const float* __restrict__ Einv_re, const float* __restrict__ Einv_im,
                         unsigned short* __restrict__ Bdt,
                         const float* __restrict__ E_re, const float* __restrict__ E_im,
                         unsigned short* __restrict__ Bet,
                         const float* __restrict__ x_re, const float* __restrict__ x_im,
                         const float* __restrict__ g, const float* __restrict__ b,
                         unsigned short* __restrict__ xnb) {
  int blk = blockIdx.x;
  int tid = threadIdx.x;
  if (blk < 1024) {
    int u = blk * 256 + tid;
    if (u < 4096) xm[u] = 0.f;            // xm_re (2048) + xm_im (2048), contiguous
    if (u >= 32 * 128 * 64) return;
    int img = u >> 13;
    int rem = u & 8191;
    int row = rem >> 6;
    int cu  = rem & 63;
    int prow = row < 64 ? row : row + 2304;
    xnb_u[((size_t)img * PADROWS + prow) * 64 + cu] = 0u;
  } else if (blk < 1600) {
    int idx = (blk - 1024) * 256 + tid;   // 147456
    int tap = idx / 16384;
    int rem = idx & 16383;
    int cout = rem >> 7, cin = rem & 127;
    float v;
    if (cout < 64) {
      if (cin < 64) v =  wc_re[((size_t)cout * 64 + cin) * 9 + tap];
      else          v = -wc_im[((size_t)cout * 64 + (cin - 64)) * 9 + tap];
    } else {
      int o = cout - 64;
      if (cin < 64) v =  wc_im[((size_t)o * 64 + cin) * 9 + tap];
      else          v =  wc_re[((size_t)o * 64 + (cin - 64)) * 9 + tap];
    }
    Wt[idx] = f2bf(v);
  } else if (blk < 2112) {
    int idx = (blk - 1600) * 256 + tid;   // 131072
    {
      int e = idx >> 15, rem = idx & 32767, j = rem >> 7, k = rem & 127;
      float v = W1[((size_t)e * 128 + k) * 256 + j];
      int sw = ((((k >> 3) ^ (j & 7)) << 3) | (k & 7));
      W1t[(size_t)e * 32768 + j * 128 + sw] = f2bf(v);
    }
    {
      int e = idx >> 15, rem = idx & 32767, c = rem >> 8, k2 = rem & 255;
      float v = W2[((size_t)e * 256 + k2) * 128 + c];
      int sw = ((((k2 >> 3) ^ (c & 7)) << 3) | (k2 & 7));
      W2t[(size_t)e * 32768 + c * 256 + sw] = f2bf(v);
    }
  } else if (blk < 2176) {
    int idx = (blk - 2112) * 256 + tid;   // 16384
    int j = idx >> 7, k = idx & 127;
    float v;
    if (j < 64) {
      if (k < 64) v =  Einv_re[k * 64 + j];
      else        v = -Einv_im[(k - 64) * 64 + j];
    } else {
      int d = j - 64;
      if (k < 64) v =  Einv_im[k * 64 + d];
      else        v =  Einv_re[(k - 64) * 64 + d];
    }
    int sw = ((((k >> 3) ^ (j & 7)) << 3) | (k & 7));
    Bdt[j * 128 + sw] = f2bf(v);
  } else if (blk < 2240) {
    int idx = (blk - 2176) * 256 + tid;   // 16384
    int j = idx >> 7, k = idx & 127;
    float v;
    if (j < 64) {
      if (k < 64) v =  E_re[k * 64 + j];
      else        v = -E_im[(k - 64) * 64 + j];
    } else {
      int d = j - 64;
      if (k < 64) v =  E_im[k * 64 + d];
      else        v =  E_re[(k - 64) * 64 + d];
    }
    int sw = ((((k >> 3) ^ (j & 7)) << 3) | (k & 7));
    Bet[j * 128 + sw] = f2bf(v);
  } else {
    // ---- LayerNorm branch, 1152 blocks ----
    int lb = blk - 2240;
    int n = lb / 36;
    int hw0 = (lb % 36) * 64;
    __shared__ float ls[64][129];
    __shared__ float part_s[4][64], part_q[4][64];
    __shared__ float mean_s[64], rstd_s[64];
    for (int i = tid; i < 64 * 128; i += 256) {
      int d = i >> 6, p = i & 63;
      float v = (d < DD) ? x_re[((size_t)n * DD + d) * HW + hw0 + p]
                         : x_im[((size_t)n * DD + (d - DD)) * HW + hw0 + p];
      ls[p][d] = v;
    }
    __syncthreads();
    {
      int p = tid & 63, q = tid >> 6;
      float s = 0.f, ss = 0.f;
      for (int c = q * 32; c < q * 32 + 32; c++) { float v = ls[p][c]; s += v; ss += v * v; }
      part_s[q][p] = s; part_q[q][p] = ss;
    }
    __syncthreads();
    if (tid < 64) {
      float s = part_s[0][tid] + part_s[1][tid] + part_s[2][tid] + part_s[3][tid];
      float ss = part_q[0][tid] + part_q[1][tid] + part_q[2][tid] + part_q[3][tid];
      float m = s * (1.f / CC);
      float var = ss * (1.f / CC) - m * m;
      mean_s[tid] = m; rstd_s[tid] = rsqrtf(var + EPS);
    }
    __syncthreads();
    for (int i = tid; i < 64 * 128; i += 256) {
      int p = i >> 7, c = i & 127;
      float v = (ls[p][c] - mean_s[p]) * rstd_s[p] * g[c] + b[c];
      xnb[(((size_t)n * PADROWS) + 64 + hw0 + p) * 128 + c] = f2bf(v);
    }
  }
}

// ---------------- K2: MFMA implicit-GEMM conv + FUSED eigen transform + mean partial ----------------
#define TM 128
#define AROWS 226

__global__ __launch_bounds__(512, 1) void k_conv(
    const unsigned short* __restrict__ xnb,
    const unsigned short* __restrict__ Wt,
    const float* __restrict__ bc_re, const float* __restrict__ bc_im,
    const float* __restrict__ metric,
    const float* __restrict__ x_re, const float* __restrict__ x_im,
    unsigned short* __restrict__ xpb,
    const unsigned short* __restrict__ Bet,
    unsigned short* __restrict__ egb_re, unsigned short* __restrict__ egb_im,
    float* __restrict__ xm_re, float* __restrict__ xm_im) {
  __shared__ unsigned short As[AROWS * 128];
  __shared__ unsigned short Bs[2][128 * 128];
  int n = blockIdx.x / 18;
  int tile = blockIdx.x % 18;
  int hw0 = tile * TM;
  int tid = threadIdx.x;
  int lane = tid & 63, wv = tid >> 6;
  int wvp = wv >> 1, wvc = wv & 1;
  int r16 = lane & 15, kgrp = lane >> 4;

  const unsigned short* xbase = xnb + ((size_t)n * PADROWS + 64 + hw0 - 49) * 128;
  for (int i = tid; i < AROWS * 16; i += 512) {
    int row = i >> 4, ch = i & 15;
    GLOAD_LDS16(xbase + (size_t)row * 128 + ((ch ^ (row & 7)) << 3), &As[i * 8]);
  }
  {
    #pragma unroll
    for (int it = 0; it < 4; it++) {
      int i = it * 512 + tid;
      int row = i >> 4, ch = i & 15;
      GLOAD_LDS16(Wt + (size_t)row * 128 + ((ch ^ (row & 7)) << 3), &Bs[0][i * 8]);
    }
  }

  f32x4 acc[2][4];
  #pragma unroll
  for (int am = 0; am < 2; am++)
    #pragma unroll
    for (int n0 = 0; n0 < 4; n0++) acc[am][n0] = (f32x4){0.f, 0.f, 0.f, 0.f};

  int w0 = (hw0 + wvp * 32 + r16) % 48;
  int w1 = (hw0 + wvp * 32 + 16 + r16) % 48;

  __syncthreads();   // As + Bs[0] staged (vmcnt drained)

  for (int tap = 0; tap < 9; tap++) {
    int cur = tap & 1;
    if (tap < 8) {
      const unsigned short* wbase = Wt + (size_t)(tap + 1) * 16384;
      #pragma unroll
      for (int it = 0; it < 4; it++) {
        int i = it * 512 + tid;
        int row = i >> 4, ch = i & 15;
        GLOAD_LDS16(wbase + (size_t)row * 128 + ((ch ^ (row & 7)) << 3), &Bs[cur ^ 1][i * 8]);
      }
    }
    int ky = tap / 3, kx = tap % 3;
    int delta = (ky - 1) * 48 + (kx - 1);
    bool v0 = (unsigned)(w0 + kx - 1) < 48u;
    bool v1 = (unsigned)(w1 + kx - 1) < 48u;
    int lp0 = wvp * 32 + r16 + delta + 49;
    int lp1 = lp0 + 16;
    __builtin_amdgcn_s_setprio(1);
    #pragma unroll
    for (int k0 = 0; k0 < 4; k0++) {
      bf16x8 a0 = {0,0,0,0,0,0,0,0}, a1 = {0,0,0,0,0,0,0,0};
      if (v0) a0 = *(const bf16x8*)(As + lp0 * 128 + (((k0 * 4 + kgrp) ^ (lp0 & 7)) << 3));
      if (v1) a1 = *(const bf16x8*)(As + lp1 * 128 + (((k0 * 4 + kgrp) ^ (lp1 & 7)) << 3));
      #pragma unroll
      for (int n0 = 0; n0 < 4; n0++) {
        int brow = wvc * 64 + n0 * 16 + r16;
        bf16x8 b = *(const bf16x8*)(&Bs[cur][brow * 128 + (((k0 * 4 + kgrp) ^ (brow & 7)) << 3)]);
        acc[0][n0] = __builtin_amdgcn_mfma_f32_16x16x32_bf16(a0, b, acc[0][n0], 0, 0, 0);
        acc[1][n0] = __builtin_amdgcn_mfma_f32_16x16x32_bf16(a1, b, acc[1][n0], 0, 0, 0);
      }
    }
    __builtin_amdgcn_s_setprio(0);
    __syncthreads();   // MFMA(tap) done + Bs[next] loads drained
  }

  // ---- issue Bet staging into dead As region (overlaps epilogue below) ----
  {
    #pragma unroll
    for (int it = 0; it < 4; it++)
      GLOAD_LDS16(Bet + (size_t)(it * 512 + tid) * 8, &As[(it * 512 + tid) * 8]);
  }
  float* red = (float*)&As[16384];   // 128 f32 mean scratch (beyond Bet's 32KB)
  if (tid < 128) red[tid] = 0.f;

  // ---- conv epilogue: bf16 xp write + bf16 -> Xe (dead Bs[0], swizzled) ----
  unsigned short* Xe = &Bs[0][0];
  #pragma unroll
  for (int am = 0; am < 2; am++) {
    int prow0 = wvp * 32 + am * 16 + kgrp * 4;
    int pix0 = hw0 + prow0;
    f32x4 mets = *(const f32x4*)(metric + pix0);
    #pragma unroll
    for (int n0 = 0; n0 < 4; n0++) {
      int col = wvc * 64 + n0 * 16 + r16;
      float bias = (col < DD) ? bc_re[col] : bc_im[col - DD];
      const float* xsrc = (col < DD) ? (x_re + ((size_t)n * DD + col) * HW)
                                     : (x_im + ((size_t)n * DD + (col - DD)) * HW);
      f32x4 xres = *(const f32x4*)(xsrc + pix0);
      #pragma unroll
      for (int j = 0; j < 4; j++) {
        float v = acc[am][n0][j] * mets[j] + bias + xres[j];
        unsigned short bv = f2bf(v);
        xpb[((size_t)n * HW + pix0 + j) * 128 + col] = bv;
        int pix = prow0 + j;
        Xe[pix * 128 + ((((col >> 3) ^ (pix & 7)) << 3) | (col & 7))] = bv;
      }
    }
  }
  __syncthreads();   // Xe visible + Bet drained + red zeroed

  // ---- eigen GEMM: 8 waves = 2 pos-halves x (2x2) wave grid ----
  {
    const unsigned short* BetL = (const unsigned short*)As;
    int half = wv >> 2, wmE = (wv >> 1) & 1, wnE = wv & 1;
    f32x4 accE[2][4];
    #pragma unroll
    for (int mt = 0; mt < 2; mt++)
      #pragma unroll
      for (int nt = 0; nt < 4; nt++) accE[mt][nt] = (f32x4){0.f, 0.f, 0.f, 0.f};
    #pragma unroll
    for (int ks = 0; ks < 4; ks++) {
      int kc = ks * 4 + kgrp;
      bf16x8 a[2], bb[4];
      #pragma unroll
      for (int mt = 0; mt < 2; mt++) {
        int r = half * 64 + wmE * 32 + mt * 16 + r16;
        a[mt] = *(const bf16x8*)&Xe[r * 128 + ((kc ^ (r & 7)) << 3)];
      }
      #pragma unroll
      for (int nt = 0; nt < 4; nt++) {
        int j = wnE * 64 + nt * 16 + r16;
        bb[nt] = *(const bf16x8*)&BetL[j * 128 + ((kc ^ (j & 7)) << 3)];
      }
      #pragma unroll
      for (int mt = 0; mt < 2; mt++)
        #pragma unroll
        for (int nt = 0; nt < 4; nt++)
          accE[mt][nt] = __builtin_amdgcn_mfma_f32_16x16x32_bf16(a[mt], bb[nt], accE[mt][nt], 0, 0, 0);
    }
    #pragma unroll
    for (int nt = 0; nt < 4; nt++) {
      int j2 = wnE * 64 + nt * 16 + r16;
      float psum = 0.f;
      #pragma unroll
      for (int mt = 0; mt < 2; mt++) {
        int row0 = half * 64 + wmE * 32 + mt * 16 + kgrp * 4;
        #pragma unroll
        for (int jj = 0; jj < 4; jj++) {
          float v = accE[mt][nt][jj];
          size_t pos = (size_t)n * HW + hw0 + row0 + jj;
          if (j2 < 64) egb_re[pos * 64 + j2] = f2bf(v);
          else         egb_im[pos * 64 + (j2 - 64)] = f2bf(v);
          psum += v;
        }
      }
      atomicAdd(&red[j2], psum);
    }
  }
  __syncthreads();
  if (tid < 128) {
    float val = red[tid] * (1.f / HW);
    if (tid < 64) atomicAdd(&xm_re[n * DD + tid], val);
    else          atomicAdd(&xm_im[n * DD + (tid - 64)], val);
  }
}

// ---------------- K5: fused flux scan + per-(b,t) src/gate matmul + od/of ----------------
__global__ void k_seq(const float* __restrict__ xm_re, const float* __restrict__ xm_im,
                      const float* __restrict__ dt, const float* __restrict__ lam_flux,
                      const float* __restrict__ inj_re, const float* __restrict__ inj_im,
                      const float* __restrict__ flux_re0, const float* __restrict__ flux_im0,
                      const float* __restrict__ Wsrc_re, const float* __restrict__ Wsrc_im,
                      const float* __restrict__ Wgate, const float* __restrict__ bgate,
                      const float* __restrict__ lam_re, const float* __restrict__ lam_im,
                      float* __restrict__ gate, float* __restrict__ src_re, float* __restrict__ src_im,
                      float* __restrict__ od_re, float* __restrict__ od_im,
                      float* __restrict__ of_re, float* __restrict__ of_im) {
  int bt = blockIdx.x;
  int b = bt / TT;
  int t = bt % TT;
  int e = threadIdx.x;
  __shared__ float fr[DD], fi[DD];
  {
    float lx = lam_flux[e];
    float sp = lx > 20.f ? lx : log1pf(expf(lx));
    float f_r = flux_re0[b * DD + e], f_i = flux_im0[b * DD + e];
    float ij_r = inj_re[e], ij_i = inj_im[e];
    for (int tp = 0; tp <= t; tp++) {
      float A = expf(-sp * dt[tp]);
      int btp = b * TT + tp;
      float xr = xm_re[btp * DD + e], xi = xm_im[btp * DD + e];
      f_r = A * f_r + (xr * ij_r - xi * ij_i);
      f_i = A * f_i + (xr * ij_i + xi * ij_r);
    }
    fr[e] = f_r; fi[e] = f_i;
  }
  __syncthreads();
  float sr = 0.f, si = 0.f, gl = bgate[e];
  for (int d2 = 0; d2 < DD; d2++) {
    float r = fr[d2], im = fi[d2];
    float wr = Wsrc_re[d2 * DD + e], wi = Wsrc_im[d2 * DD + e];
    sr += r * wr - im * wi;
    si += r * wi + im * wr;
    gl += r * Wgate[d2 * DD + e];
  }
  src_re[bt * DD + e] = sr; src_im[bt * DD + e] = si;
  gate[bt * DD + e] = 1.f / (1.f + expf(-gl));
  float lre = lam_re[e];
  float lr_v = -(lre > 20.f ? lre : log1pf(expf(lre)));
  float li_v = lam_im[e];
  float den = lr_v * lr_v + li_v * li_v;
  float dtv = dt[t];
  float mag = expf(lr_v * dtv);
  float odr = mag * cosf(li_v * dtv);
  float odi = mag * sinf(li_v * dtv);
  od_re[bt * DD + e] = odr; od_im[bt * DD + e] = odi;
  of_re[bt * DD + e] = ((odr - 1.f) * lr_v + odi * li_v) / den;
  of_im[bt * DD + e] = (odi * lr_v - (odr - 1.f) * li_v) / den;
}

// ---------------- K6: forcing + time scan; bf16 eg in, pre-swizzled bf16 ub out ----------------
__global__ void k_uscan(const unsigned short* __restrict__ egb_re,
                        const unsigned short* __restrict__ egb_im,
                        unsigned short* __restrict__ ub,
                        const float* __restrict__ gate,
                        const float* __restrict__ src_re, const float* __restrict__ src_im,
                        const float* __restrict__ od_re, const float* __restrict__ od_im,
                        const float* __restrict__ of_re, const float* __restrict__ of_im,
                        const float* __restrict__ h_re, const float* __restrict__ h_im) {
  size_t gid = (size_t)blockIdx.x * 256 + threadIdx.x;
  int e = (int)(gid & 63);
  size_t rem = gid >> 6;
  int hw = (int)(rem % HW);
  int b = (int)(rem / HW);
  float u_r = 0.f, u_i = 0.f;
  for (int t = 0; t < TT; t++) {
    int bt = b * TT + t;
    size_t idx = ((size_t)bt * HW + hw) * DD + e;
    float g = gate[bt * DD + e];
    float fr2 = bf2f(egb_re[idx]) * g + src_re[bt * DD + e] * (1.f - g);
    float fi2 = bf2f(egb_im[idx]) * g + src_im[bt * DD + e] * (1.f - g);
    float ofr = of_re[bt * DD + e], ofi = of_im[bt * DD + e];
    float ut_r = fr2 * ofr - fi2 * ofi;
    float ut_i = fr2 * ofi + fi2 * ofr;
    float odr = od_re[bt * DD + e], odi = od_im[bt * DD + e];
    if (t == 0) {
      size_t hidx = ((size_t)b * HW + hw) * DD + e;
      float hr = h_re[hidx], hi = h_im[hidx];
      ut_r += hr * odr - hi * odi;
      ut_i += hr * odi + hi * odr;
    }
    float nu_r = odr * u_r - odi * u_i + ut_r;
    float nu_i = odr * u_i + odi * u_r + ut_i;
    u_r = nu_r; u_i = nu_i;
    size_t pos = (size_t)bt * HW + hw;
    int p7 = (int)(pos & 7);
    int swr = (((e >> 3) ^ p7) << 3) | (e & 7);
    int swi = ((((64 + e) >> 3) ^ p7) << 3) | (e & 7);
    ub[pos * 128 + swr] = f2bf(u_r);
    ub[pos * 128 + swi] = f2bf(u_i);
  }
}

// ---------------- K78: FUSED decode(MFMA)+LN2+gates + MFMA MoE; y via acc2 init ----------------
__global__ __launch_bounds__(256, 2) void k_dmoe(
    const unsigned short* __restrict__ ub,
    const unsigned short* __restrict__ Bdt,
    const float* __restrict__ Wg,
    float* __restrict__ gates,
    const unsigned short* __restrict__ xpb,
    const unsigned short* __restrict__ W1t, const unsigned short* __restrict__ W2t,
    const float* __restrict__ b1, const float* __restrict__ b2,
    const float* __restrict__ gt_g, const float* __restrict__ gt_b,
    float* __restrict__ out) {
  __shared__ __attribute__((aligned(16))) unsigned char smem[81920];
  int tid = threadIdx.x;
  int blk = blockIdx.x;
  int n = blk / 36;
  int hw0 = (blk % 36) * 64;
  size_t pos0 = (size_t)blk * 64;
  int lane = tid & 63, w = tid >> 6, wm = w >> 1, wn = w & 1;
  int r16 = lane & 15, kgrp = lane >> 4;

  // ================= Phase D: MFMA decode + LN2 + gates; y -> Yl, X -> Xb =================
  {
    unsigned short* BdL = (unsigned short*)smem;            // 32 KB [j][k sw]
    unsigned short* Au  = (unsigned short*)(smem + 32768);  // 16 KB [p][k sw]
    #pragma unroll
    for (int it = 0; it < 8; it++)
      GLOAD_LDS16(Bdt + (size_t)(it * 256 + tid) * 8, &BdL[(it * 256 + tid) * 8]);
    #pragma unroll
    for (int it = 0; it < 4; it++)
      GLOAD_LDS16(ub + pos0 * 128 + (size_t)(it * 256 + tid) * 8, &Au[(it * 256 + tid) * 8]);
    __syncthreads();   // Au + BdL staged (vmcnt drained by syncthreads)
    f32x4 accD[2][4];
    #pragma unroll
    for (int mt = 0; mt < 2; mt++)
      #pragma unroll
      for (int nt = 0; nt < 4; nt++) accD[mt][nt] = (f32x4){0.f, 0.f, 0.f, 0.f};
    #pragma unroll
    for (int ks = 0; ks < 4; ks++) {
      int kc = ks * 4 + kgrp;
      bf16x8 a[2], bb[4];
      #pragma unroll
      for (int mt = 0; mt < 2; mt++) {
        int r = wm * 32 + mt * 16 + r16;
        a[mt] = *(const bf16x8*)&Au[r * 128 + ((kc ^ (r & 7)) << 3)];
      }
      #pragma unroll
      for (int nt = 0; nt < 4; nt++) {
        int j = wn * 64 + nt * 16 + r16;
        bb[nt] = *(const bf16x8*)&BdL[j * 128 + ((kc ^ (j & 7)) << 3)];
      }
      #pragma unroll
      for (int mt = 0; mt < 2; mt++)
        #pragma unroll
        for (int nt = 0; nt < 4; nt++)
          accD[mt][nt] = __builtin_amdgcn_mfma_f32_16x16x32_bf16(a[mt], bb[nt], accD[mt][nt], 0, 0, 0);
    }
    __syncthreads();   // all Au/BdL reads done — regions reusable
    float* DsD = (float*)smem;                      // 32 KB [p][c] linear (over BdL)
    #pragma unroll
    for (int mt = 0; mt < 2; mt++) {
      int row0 = wm * 32 + mt * 16 + kgrp * 4;
      #pragma unroll
      for (int nt = 0; nt < 4; nt++) {
        int c = wn * 64 + nt * 16 + r16;
        #pragma unroll
        for (int jj = 0; jj < 4; jj++)
          DsD[(row0 + jj) * 128 + c] = accD[mt][nt][jj];
      }
    }
    __syncthreads();   // C in LDS
    float* Yl = (float*)(smem + 32768);                    // 32 KB (Au region, dead)
    unsigned short* Xb = (unsigned short*)(smem + 65536);  // 16 KB
    int egq = tid & 15, pg = tid >> 4;
    int d0 = egq * 4, swz = pg & 7;
    f32x4 gg0 = *(const f32x4*)(gt_g + d0);
    f32x4 gb0 = *(const f32x4*)(gt_b + d0);
    f32x4 gg1 = *(const f32x4*)(gt_g + 64 + d0);
    f32x4 gb1 = *(const f32x4*)(gt_b + 64 + d0);
    f32x4 wgr[4], wgi[4];
    #pragma unroll
    for (int j = 0; j < 4; j++) {
      wgr[j] = *(const f32x4*)&Wg[(d0 + j) * 4];
      wgi[j] = *(const f32x4*)&Wg[(64 + d0 + j) * 4];
    }
    int cre = ((d0 >> 3) ^ swz) << 3;
    int cim = (((64 + d0) >> 3) ^ swz) << 3;
    int off47 = d0 & 7;   // 0 or 4
    #pragma unroll
    for (int i = 0; i < 4; i++) {
      int p = pg + 16 * i;
      size_t pos = pos0 + p;
      f32x4 acr = *(const f32x4*)&DsD[p * 128 + d0];
      f32x4 aci = *(const f32x4*)&DsD[p * 128 + 64 + d0];
      float s = acr[0] + acr[1] + acr[2] + acr[3]
              + aci[0] + aci[1] + aci[2] + aci[3];
      float q = acr[0]*acr[0] + acr[1]*acr[1] + acr[2]*acr[2] + acr[3]*acr[3]
              + aci[0]*aci[0] + aci[1]*aci[1] + aci[2]*aci[2] + aci[3]*aci[3];
      #pragma unroll
      for (int off = 8; off >= 1; off >>= 1) {
        s += __shfl_xor(s, off);
        q += __shfl_xor(q, off);
      }
      float mean = s * (1.f / CC);
      float rstd = rsqrtf(q * (1.f / CC) - mean * mean + EPS);
      f32x4 lnr = (acr - mean) * rstd * gg0 + gb0;
      f32x4 lni = (aci - mean) * rstd * gg1 + gb1;
      *(f32x4*)&Yl[p * 128 + d0] = lnr;          // y, linear layout
      *(f32x4*)&Yl[p * 128 + 64 + d0] = lni;
      f32x4 p4 = lnr[0]*wgr[0] + lnr[1]*wgr[1] + lnr[2]*wgr[2] + lnr[3]*wgr[3]
               + lni[0]*wgi[0] + lni[1]*wgi[1] + lni[2]*wgi[2] + lni[3]*wgi[3];
      float p0 = p4[0], p1 = p4[1], p2 = p4[2], p3 = p4[3];
      #pragma unroll
      for (int off = 8; off >= 1; off >>= 1) {
        p0 += __shfl_xor(p0, off); p1 += __shfl_xor(p1, off);
        p2 += __shfl_xor(p2, off); p3 += __shfl_xor(p3, off);
      }
      if (egq == 0) {
        float m = fmaxf(fmaxf(p0, p1), fmaxf(p2, p3));
        float e0v = __expf(p0 - m), e1v = __expf(p1 - m), e2v = __expf(p2 - m), e3v = __expf(p3 - m);
        float inv = 1.f / (e0v + e1v + e2v + e3v);
        f32x4 g4 = {e0v * inv, e1v * inv, e2v * inv, e3v * inv};
        *(f32x4*)(gates + pos * 4) = g4;
      }
      unsigned int r0 = (unsigned int)f2bf(lnr[0]) | ((unsigned int)f2bf(lnr[1]) << 16);
      unsigned int r1 = (unsigned int)f2bf(lnr[2]) | ((unsigned int)f2bf(lnr[3]) << 16);
      unsigned int i0 = (unsigned int)f2bf(lni[0]) | ((unsigned int)f2bf(lni[1]) << 16);
      unsigned int i1 = (unsigned int)f2bf(lni[2]) | ((unsigned int)f2bf(lni[3]) << 16);
      *(uint2v*)&Xb[p * 128 + cre + off47] = (uint2v){r0, r1};
      *(uint2v*)&Xb[p * 128 + cim + off47] = (uint2v){i0, i1};
    }
  }
  __syncthreads();   // Yl + Xb complete; gates globally visible

  // ================= Transition: acc2 <- Yl; xa <- Xb; then stage W1[0] =================
  unsigned short* W1s = (unsigned short*)smem;             // 32 KB (over DsD)
  unsigned short* W2s = (unsigned short*)(smem + 32768);   // 32 KB (over Yl after read)
  unsigned short* Hs  = (unsigned short*)(smem + 65536);   // 16 KB (over Xb after read)
  float* Ds = (float*)smem;                                // 33 KB, reused after MoE loop
  f32x4 acc2[2][4];
  {
    const float* YlF = (const float*)(smem + 32768);
    #pragma unroll
    for (int mt = 0; mt < 2; mt++) {
      int row0 = wm * 32 + mt * 16 + kgrp * 4;
      #pragma unroll
      for (int nt = 0; nt < 4; nt++) {
        int c = wn * 64 + nt * 16 + r16;
        #pragma unroll
        for (int jj = 0; jj < 4; jj++)
          acc2[mt][nt][jj] = YlF[(row0 + jj) * 128 + c];
      }
    }
  }
  bf16x8 xa[2][4];   // [pt][ks]
  {
    const unsigned short* Xb = (const unsigned short*)(smem + 65536);
    #pragma unroll
    for (int pt = 0; pt < 2; pt++) {
      int r = wm * 32 + pt * 16 + r16;
      #pragma unroll
      for (int ks = 0; ks < 4; ks++) {
        int kc = ks * 4 + kgrp;
        xa[pt][ks] = *(const bf16x8*)&Xb[r * 128 + ((kc ^ (r & 7)) << 3)];
      }
    }
  }
  __syncthreads();   // Yl/Xb reads done — safe to overwrite
  {
    #pragma unroll
    for (int it = 0; it < 8; it++)
      GLOAD_LDS16(W1t + (size_t)(it * 256 + tid) * 8, &W1s[(it * 256 + tid) * 8]);
  }
  __syncthreads();   // W1[0] drained

  // ================= Phase M: MoE loop (r7 core; acc2 pre-loaded with y) =================
  const float c1 = -2.3022084f;
  const float c2 = -0.10294372f;

  for (int s = 0; s < 8; s++) {
    int e = s >> 1, h = s & 1;
    float grp[2];
    #pragma unroll
    for (int pt = 0; pt < 2; pt++)
      grp[pt] = gates[(pos0 + wm * 32 + pt * 16 + r16) * 4 + e];
    f32x4 b1p[4];
    #pragma unroll
    for (int ft = 0; ft < 4; ft++)
      b1p[ft] = *(const f32x4*)&b1[e * 256 + h * 128 + wn * 64 + ft * 16 + kgrp * 4];
    {
      const unsigned short* w2src = W2t + (size_t)e * 32768 + (size_t)h * 128;
      #pragma unroll
      for (int it = 0; it < 8; it++) {
        int i = it * 256 + tid;
        int c = i >> 4, j = i & 15;
        GLOAD_LDS16(w2src + (size_t)c * 256 + j * 8, &W2s[i * 8]);
      }
    }
    f32x4 acc1[4][2];
    #pragma unroll
    for (int ft = 0; ft < 4; ft++)
      #pragma unroll
      for (int pt = 0; pt < 2; pt++) acc1[ft][pt] = (f32x4){0.f, 0.f, 0.f, 0.f};
    __builtin_amdgcn_s_setprio(1);
    #pragma unroll
    for (int ks = 0; ks < 4; ks++) {
      int kc = ks * 4 + kgrp;
      bf16x8 wf[4];
      #pragma unroll
      for (int ft = 0; ft < 4; ft++) {
        int fr = wn * 64 + ft * 16 + r16;
        wf[ft] = *(const bf16x8*)&W1s[fr * 128 + ((kc ^ (fr & 7)) << 3)];
      }
      #pragma unroll
      for (int ft = 0; ft < 4; ft++)
        #pragma unroll
        for (int pt = 0; pt < 2; pt++)
          acc1[ft][pt] = __builtin_amdgcn_mfma_f32_16x16x32_bf16(wf[ft], xa[pt][ks], acc1[ft][pt], 0, 0, 0);
    }
    __builtin_amdgcn_s_setprio(0);
    #pragma unroll
    for (int ft = 0; ft < 4; ft++) {
      int f0 = wn * 64 + ft * 16 + kgrp * 4;
      int chunk = f0 >> 3, sub = f0 & 7;
      #pragma unroll
      for (int pt = 0; pt < 2; pt++) {
        int pl = wm * 32 + pt * 16 + r16;
        float gr = grp[pt];
        unsigned short hb[4];
        #pragma unroll
        for (int jj = 0; jj < 4; jj++) {
          float x = acc1[ft][pt][jj] + b1p[ft][jj];
          float z = x * (c1 + c2 * x * x);
          float t = __builtin_amdgcn_exp2f(z);
          hb[jj] = f2bf(x * gr * __builtin_amdgcn_rcpf(1.f + t));
        }
        unsigned int lo = (unsigned int)hb[0] | ((unsigned int)hb[1] << 16);
        unsigned int hi = (unsigned int)hb[2] | ((unsigned int)hb[3] << 16);
        *(uint2v*)&Hs[pl * 128 + ((chunk ^ (pl & 7)) << 3) + sub] = (uint2v){lo, hi};
      }
    }
    __syncthreads();   // Hs ready; W2 stage drained; W1s consumed
    if (s < 7) {
      int sn = s + 1;
      const unsigned short* w1src = W1t + (size_t)(sn >> 1) * 32768 + (size_t)(sn & 1) * 16384;
      #pragma unroll
      for (int it = 0; it < 8; it++)
        GLOAD_LDS16(w1src + (size_t)(it * 256 + tid) * 8, &W1s[(it * 256 + tid) * 8]);
    }
    __builtin_amdgcn_s_setprio(1);
    #pragma unroll
    for (int ks = 0; ks < 4; ks++) {
      int kc = ks * 4 + kgrp;
      bf16x8 a[2], bb[4];
      #pragma unroll
      for (int mt = 0; mt < 2; mt++) {
        int r = wm * 32 + mt * 16 + r16;
        a[mt] = *(const bf16x8*)&Hs[r * 128 + ((kc ^ (r & 7)) << 3)];
      }
      #pragma unroll
      for (int nt = 0; nt < 4; nt++) {
        int c = wn * 64 + nt * 16 + r16;
        bb[nt] = *(const bf16x8*)&W2s[c * 128 + ((kc ^ (c & 7)) << 3)];
      }
      #pragma unroll
      for (int mt = 0; mt < 2; mt++)
        #pragma unroll
        for (int nt = 0; nt < 4; nt++)
          acc2[mt][nt] = __builtin_amdgcn_mfma_f32_16x16x32_bf16(a[mt], bb[nt], acc2[mt][nt], 0, 0, 0);
    }
    __builtin_amdgcn_s_setprio(0);
    __syncthreads();
  }

  // ---- LDS-transposed final epilogue (acc2 already holds y + delta) ----
  #pragma unroll
  for (int mt = 0; mt < 2; mt++) {
    int row0 = wm * 32 + mt * 16 + kgrp * 4;
    #pragma unroll
    for (int nt = 0; nt < 4; nt++) {
      int c = wn * 64 + nt * 16 + r16;
      #pragma unroll
      for (int jj = 0; jj < 4; jj++)
        Ds[(row0 + jj) * 129 + c] = acc2[mt][nt][jj];
    }
  }
  __syncthreads();
  #pragma unroll
  for (int it = 0; it < 8; it++) {
    int qi = it * 256 + tid;
    int p = qi >> 5, cq = (qi & 31) << 2;
    size_t pos = pos0 + p;
    const unsigned short* xr = &xpb[pos * 128 + cq];
    f32x4 xpv = {bf2f(xr[0]), bf2f(xr[1]), bf2f(xr[2]), bf2f(xr[3])};
    f32x4 g4  = *(const f32x4*)&gates[pos * 4];
    f32x4 bt0 = *(const f32x4*)&b2[0 * CC + cq];
    f32x4 bt1 = *(const f32x4*)&b2[1 * CC + cq];
    f32x4 bt2 = *(const f32x4*)&b2[2 * CC + cq];
    f32x4 bt3 = *(const f32x4*)&b2[3 * CC + cq];
    int base = p * 129 + cq;
    #pragma unroll
    for (int j = 0; j < 4; j++) {
      float bterm = g4[0] * bt0[j] + g4[1] * bt1[j] + g4[2] * bt2[j] + g4[3] * bt3[j];
      Ds[base + j] = xpv[j] + Ds[base + j] + bterm;
    }
  }
  __syncthreads();
  {
    int p = tid & 63;
    int cg = tid >> 6;
    const float* Drow = Ds + p * 129;
    size_t obase = ((size_t)n * CC) * HW + hw0 + p;
    #pragma unroll
    for (int i = 0; i < 32; i++) {
      int c = i * 4 + cg;
      out[obase + (size_t)c * HW] = Drow[c];
    }
  }
}

extern "C" void kernel_launch(void* const* d_in, const int* in_sizes, int n_in,
                              void* d_out, int out_size, void* d_ws, size_t ws_size,
                              hipStream_t stream) {
  const float* x_re   = (const float*)d_in[0];
  const float* x_im   = (const float*)d_in[1];
  const float* h_re   = (const float*)d_in[2];
  const float* h_im   = (const float*)d_in[3];
  const float* flux_re= (const float*)d_in[4];
  const float* flux_im= (const float*)d_in[5];
  const float* dt     = (const float*)d_in[6];
  const float* gs_g   = (const float*)d_in[7];
  const float* gs_b   = (const float*)d_in[8];
  const float* wc_re  = (const float*)d_in[9];
  const float* wc_im  = (const float*)d_in[10];
  const float* bc_re  = (const float*)d_in[11];
  const float* bc_im  = (const float*)d_in[12];
  const float* metric = (const float*)d_in[13];
  const float* gt_g   = (const float*)d_in[14];
  const float* gt_b   = (const float*)d_in[15];
  const float* E_re   = (const float*)d_in[16];
  const float* E_im   = (const float*)d_in[17];
  const float* Einv_re= (const float*)d_in[18];
  const float* Einv_im= (const float*)d_in[19];
  const float* lam_flux=(const float*)d_in[20];
  const float* inj_re = (const float*)d_in[21];
  const float* inj_im = (const float*)d_in[22];
  const float* Wsrc_re= (const float*)d_in[23];
  const float* Wsrc_im= (const float*)d_in[24];
  const float* Wgate  = (const float*)d_in[25];
  const float* bgate  = (const float*)d_in[26];
  const float* lam_re = (const float*)d_in[27];
  const float* lam_im = (const float*)d_in[28];
  const float* Wg     = (const float*)d_in[29];
  const float* W1     = (const float*)d_in[30];
  const float* b1     = (const float*)d_in[31];
  const float* W2     = (const float*)d_in[32];
  const float* b2     = (const float*)d_in[33];

  float* ws = (float*)d_ws;
  const size_t SZ_FULL = (size_t)NBT * HW * CC;   // 9,437,184
  const size_t SZ_HALF = (size_t)NBT * HW * DD;   // 4,718,592
  // Regions keep their f32-sized slots (layout unchanged); xp/eg hold bf16.
  float* xp    = ws;                    // bf16 [pos][128] (half-used slot)
  float* eg_re = xp + SZ_FULL;          // bf16 (half-used slot)
  float* eg_im = eg_re + SZ_HALF;       // bf16 (half-used slot)
  float* xr2   = eg_im + SZ_HALF;       // aliases xnb (bf16) + Wt (bf16) + ub (bf16)
  unsigned short* xnb = (unsigned short*)xr2;
  unsigned short* Wt  = (unsigned short*)(xr2 + 5000000);
  unsigned short* ub  = (unsigned short*)xr2;   // over xnb (dead after k_conv)
  float* smalls = xr2 + SZ_FULL;
  float* xm_re = smalls;
  float* xm_im = xm_re + 2048;
  float* gatep = xm_im + 2048;
  float* src_re= gatep + 2048;
  float* src_im= src_re + 2048;
  float* od_re = src_im + 2048;
  float* od_im = od_re + 2048;
  float* of_re = od_im + 2048;
  float* of_im = of_re + 2048;
  float* gates = of_im + 2048;
  unsigned short* W1t = (unsigned short*)(gates + (size_t)NBT * HW * 4);
  unsigned short* W2t = W1t + 131072;
  unsigned short* Bdt = W2t + 131072;   // 16384 bf16
  unsigned short* Bet = Bdt + 16384;    // 16384 bf16

  unsigned short* xpb    = (unsigned short*)xp;
  unsigned short* egb_re = (unsigned short*)eg_re;
  unsigned short* egb_im = (unsigned short*)eg_im;

  hipLaunchKernelGGL(k_prepln, dim3(3392), dim3(256), 0, stream,
                     (unsigned int*)xnb, xm_re, wc_re, wc_im, Wt, W1, W2, W1t, W2t,
                     Einv_re, Einv_im, Bdt, E_re, E_im, Bet,
                     x_re, x_im, gs_g, gs_b, xnb);
  hipLaunchKernelGGL(k_conv, dim3(NBT * 18), dim3(512), 0, stream,
                     xnb, Wt, bc_re, bc_im, metric, x_re, x_im, xpb,
                     Bet, egb_re, egb_im, xm_re, xm_im);
  hipLaunchKernelGGL(k_seq, dim3(NBT), dim3(DD), 0, stream,
                     xm_re, xm_im, dt, lam_flux, inj_re, inj_im, flux_re, flux_im,
                     Wsrc_re, Wsrc_im, Wgate, bgate, lam_re, lam_im,
                     gatep, src_re, src_im, od_re, od_im, of_re, of_im);
  hipLaunchKernelGGL(k_uscan, dim3(1152), dim3(256), 0, stream,
                     egb_re, egb_im, ub, gatep, src_re, src_im, od_re, od_im, of_re, of_im,
                     h_re, h_im);
  hipLaunchKernelGGL(k_dmoe, dim3(1152), dim3(256), 0, stream,
                     ub, Bdt, Wg,
                     gates, xpb, W1t, W2t, b1, b2, gt_g, gt_b,
                     (float*)d_out);
}